// Round 11
// baseline (225.754 us; speedup 1.0000x reference)
//
#include <hip/hip_runtime.h>
#include <math.h>

#define D_MODEL 1024
#define NUM_HEADS 16
#define D_HEAD 64
#define SEQ 2048
#define BATCH 2
#define NROWS (BATCH * SEQ) /* 4096 */

typedef short s8v __attribute__((ext_vector_type(8)));   // 8 bf16 (4 VGPRs)
typedef float f4v __attribute__((ext_vector_type(4)));   // MFMA C/D

__device__ __forceinline__ short to_bf(float f) {
    union { float f; unsigned u; } x; x.f = f;
    unsigned r = x.u + 0x7fffu + ((x.u >> 16) & 1u);   // RNE
    return (short)(r >> 16);
}

__device__ __forceinline__ unsigned pack_bf2(float a, float b) {
    return (unsigned)(unsigned short)to_bf(a) | ((unsigned)(unsigned short)to_bf(b) << 16);
}

// raw v_exp_f32 (exp2): 1 instruction vs OCML exp2f's denormal-fixup path
__device__ __forceinline__ float fast_exp2(float x) {
    return __builtin_amdgcn_exp2f(x);
}

// async global->LDS, 16 B/lane; LDS dest is wave-uniform base + lane*16
__device__ __forceinline__ void gld_lds16(const short* g, short* l) {
    __builtin_amdgcn_global_load_lds(
        (const __attribute__((address_space(1))) unsigned*)g,
        (__attribute__((address_space(3))) unsigned*)l, 16, 0, 0);
}

// Q pre-scale: 1/sqrt(Dh) * log2(e)  -> S leaves MFMA in exp2 domain
#define QSCALE 0.180336880f

// ---------------------------------------------------------------------------
// fp32 -> bf16 convert. Wq segment pre-scaled by QSCALE.
// ---------------------------------------------------------------------------
__global__ __launch_bounds__(256) void cvt_fused(
    const float* __restrict__ x,  const float* __restrict__ Wq,
    const float* __restrict__ Wk, const float* __restrict__ Wv,
    const float* __restrict__ Wo,
    short* __restrict__ Xb, short* __restrict__ Wqkvb, short* __restrict__ Wob)
{
    const int NX = NROWS * D_MODEL / 4;
    const int NW = D_MODEL * D_MODEL / 4;
    int j = blockIdx.x * 256 + threadIdx.x;
    const float* src; short* dst; float sc = 1.f;
    if (j < NX)                 { src = x;  dst = Xb; }
    else if ((j -= NX) < NW)    { src = Wq; dst = Wqkvb; sc = QSCALE; }
    else if ((j -= NW) < NW)    { src = Wk; dst = Wqkvb + NW * 4; }
    else if ((j -= NW) < NW)    { src = Wv; dst = Wqkvb + NW * 8; }
    else                        { j -= NW; src = Wo; dst = Wob; }
    float4 v = ((const float4*)src)[j];
    short4 s = { to_bf(v.x * sc), to_bf(v.y * sc), to_bf(v.z * sc), to_bf(v.w * sc) };
    ((short4*)dst)[j] = s;
}

// ---------------------------------------------------------------------------
// QKV bf16 MFMA GEMM (unchanged from R10): 128x128, BK=64, XOR-swizzled LDS,
// XCD-locality grid (768 blocks).  Q/K: transposed accumulate -> direct 8-B
// stores into [B,H,S,Dh].  V: normal -> direct stores into V^T [B,H,Dh,S].
// ---------------------------------------------------------------------------
__global__ __launch_bounds__(256) void gemm_qkv(
    const short* __restrict__ Xb, const short* __restrict__ Wb,
    const float* __restrict__ B0, const float* __restrict__ B1, const float* __restrict__ B2,
    short* __restrict__ Q0, short* __restrict__ K1, short* __restrict__ V2)
{
    __shared__ __align__(16) short As[128 * 64];   // 16 KB
    __shared__ __align__(16) short Bs[128 * 64];   // 16 KB

    const int t    = threadIdx.x;
    const int w    = t >> 6;
    const int lane = t & 63;
    const int quad = lane >> 4;
    const int l15  = lane & 15;
    const int wm   = w & 1, wn = w >> 1;

    const int bx    = blockIdx.x;
    const int xcd   = bx & 7;
    const int g_    = bx >> 3;            // 0..95
    const int n_loc = g_ % 12;
    const int m_loc = g_ / 12;            // 0..7
    const int n0 = ((xcd >> 2) * 12 + n_loc) * 128;
    const int m0 = ((xcd & 3) * 8 + m_loc) * 128;

    const bool swapT = (n0 < 2048);       // Q/K -> transposed accumulate

    f4v acc[4][4];
#pragma unroll
    for (int i = 0; i < 4; ++i)
#pragma unroll
        for (int j = 0; j < 4; ++j) acc[i][j] = (f4v){0.f, 0.f, 0.f, 0.f};

    for (int k0 = 0; k0 < D_MODEL; k0 += 64) {
#pragma unroll
        for (int i = 0; i < 4; ++i) {
            const int cid = i * 256 + t;
            const int row = cid >> 3, kc = cid & 7, g = kc ^ (row & 7);
            gld_lds16(&Xb[(size_t)(m0 + row) * D_MODEL + k0 + g * 8],
                      &As[(i * 256 + w * 64) * 8]);
            gld_lds16(&Wb[(size_t)(n0 + row) * D_MODEL + k0 + g * 8],
                      &Bs[(i * 256 + w * 64) * 8]);
        }
        __syncthreads();

#pragma unroll
        for (int c = 0; c < 2; ++c) {
            s8v af[4], bf[4];
            const int pos = ((c * 4 + quad) ^ (l15 & 7)) * 8;
#pragma unroll
            for (int mi = 0; mi < 4; ++mi)
                af[mi] = *(const s8v*)&As[(wm * 64 + mi * 16 + l15) * 64 + pos];
#pragma unroll
            for (int ni = 0; ni < 4; ++ni)
                bf[ni] = *(const s8v*)&Bs[(wn * 64 + ni * 16 + l15) * 64 + pos];
            if (swapT) {
#pragma unroll
                for (int mi = 0; mi < 4; ++mi)
#pragma unroll
                    for (int ni = 0; ni < 4; ++ni)
                        acc[mi][ni] = __builtin_amdgcn_mfma_f32_16x16x32_bf16(
                            bf[ni], af[mi], acc[mi][ni], 0, 0, 0);
            } else {
#pragma unroll
                for (int mi = 0; mi < 4; ++mi)
#pragma unroll
                    for (int ni = 0; ni < 4; ++ni)
                        acc[mi][ni] = __builtin_amdgcn_mfma_f32_16x16x32_bf16(
                            af[mi], bf[ni], acc[mi][ni], 0, 0, 0);
            }
        }
        __syncthreads();
    }

    if (swapT) {
        const int sel = n0 >> 10;                   // 0 or 1
        const float* bias = sel == 0 ? B0 : B1;
        short* out        = sel == 0 ? Q0 : K1;
        const float bsc   = sel == 0 ? QSCALE : 1.f;
        const int nb = n0 & 1023;
#pragma unroll
        for (int ni = 0; ni < 4; ++ni) {
            const int colb = nb + wn * 64 + ni * 16 + quad * 4;   // 4-aligned
            float4 bv = *(const float4*)&bias[colb];
            const int h = colb >> 6, dh = colb & 63;
#pragma unroll
            for (int mi = 0; mi < 4; ++mi) {
                const int row = m0 + wm * 64 + mi * 16 + l15;
                const int bb = row >> 11, sl = row & (SEQ - 1);
                int2 pk;
                pk.x = (int)pack_bf2(acc[mi][ni][0] + bv.x * bsc,
                                     acc[mi][ni][1] + bv.y * bsc);
                pk.y = (int)pack_bf2(acc[mi][ni][2] + bv.z * bsc,
                                     acc[mi][ni][3] + bv.w * bsc);
                *(int2*)&out[(((size_t)(bb * NUM_HEADS + h) * SEQ) + sl) * D_HEAD + dh] = pk;
            }
        }
    } else {
        const int nb = n0 & 1023;
#pragma unroll
        for (int ni = 0; ni < 4; ++ni) {
            const int col = nb + wn * 64 + ni * 16 + l15;
            const int h = col >> 6, dh = col & 63;
            const float bv = B2[col];
#pragma unroll
            for (int mi = 0; mi < 4; ++mi) {
                const int row = m0 + wm * 64 + mi * 16 + quad * 4;
                const int bb = row >> 11, sl = row & (SEQ - 1);
                int2 pk;
                pk.x = (int)pack_bf2(acc[mi][ni][0] + bv, acc[mi][ni][1] + bv);
                pk.y = (int)pack_bf2(acc[mi][ni][2] + bv, acc[mi][ni][3] + bv);
                *(int2*)&V2[((size_t)(bb * NUM_HEADS + h) * D_HEAD + dh) * SEQ + sl] = pk;
            }
        }
    }
}

// ---------------------------------------------------------------------------
// MFMA flash attention v7: BARRIER-FREE. K and V^T fragments are loaded
// directly from global (L2/L3-resident: 512 KB per (b,h)) into MFMA operand
// registers -- no LDS staging, no __syncthreads, so the compiler can hold
// loads in flight with fine-grained vmcnt instead of draining at a barrier.
// P round-trips through wave-private LDS only (in-order DS, no barrier).
// Key-split flash-decoding, 1024 blocks, fixed-shift additive partials.
// ---------------------------------------------------------------------------
__global__ __launch_bounds__(256) void attn_mfma(
    const short* __restrict__ Qg, const short* __restrict__ Kg,
    const short* __restrict__ Vg,
    short* __restrict__ Op0, short* __restrict__ Op1, float* __restrict__ Lp)
{
    __shared__ __align__(16) short Ps[4][32 * 72];   // 18 KB, per-wave [q][key64]

    const int t    = threadIdx.x;
    const int w    = t >> 6;
    const int lane = t & 63;
    const int quad = lane >> 4;
    const int l15  = lane & 15;

    const int bidx = blockIdx.x;
    const int seg  = bidx >> 9;               // key parity
    const int p    = bidx & 255;
    const int bh   = p >> 3;
    const int pair = p & 7;
    const int qt   = ((bidx >> 8) & 1) ? 15 - pair : pair;

    const short* qbase = Qg + (size_t)bh * SEQ * D_HEAD;
    const short* kbase = Kg + (size_t)bh * SEQ * D_HEAD;
    const short* vbase = Vg + (size_t)bh * D_HEAD * SEQ;
    const int q0 = qt * 128;
    const int qw = w * 32;

    // Q fragments (B-operand layout: lane = query, regs = d). QSCALE pre-folded.
    s8v aq[2][2];
#pragma unroll
    for (int ns = 0; ns < 2; ++ns)
#pragma unroll
        for (int c = 0; c < 2; ++c)
            aq[ns][c] = *(const s8v*)&qbase[(size_t)(q0 + qw + ns * 16 + l15) * D_HEAD
                                            + c * 32 + quad * 8];

    f4v Oacc[2][4];
#pragma unroll
    for (int ms = 0; ms < 2; ++ms)
#pragma unroll
        for (int nt = 0; nt < 4; ++nt) Oacc[ms][nt] = (f4v){0.f, 0.f, 0.f, 0.f};
    float lsum[2] = {0.f, 0.f};

    for (int j = seg; j <= qt; j += 2) {
        const int k0 = j * 128;
        const bool diag = (j == qt);

#pragma unroll
        for (int half = 0; half < 2; ++half) {
            // ---- load all 8 K-frags for these 64 keys (direct from global) ----
            s8v ka[4][2];
#pragma unroll
            for (int mt = 0; mt < 4; ++mt) {
                const int krow = k0 + half * 64 + mt * 16 + l15;
                const short* kr = &kbase[(size_t)krow * D_HEAD + quad * 8];
                ka[mt][0] = *(const s8v*)kr;
                ka[mt][1] = *(const s8v*)(kr + 32);
            }
            // ---- S^T = K·Q^T (exp2 domain); exp; truncate-pack; b64 store ----
#pragma unroll
            for (int mt = 0; mt < 4; ++mt) {
#pragma unroll
                for (int ns = 0; ns < 2; ++ns) {
                    f4v st = (f4v){0.f, 0.f, 0.f, 0.f};
                    st = __builtin_amdgcn_mfma_f32_16x16x32_bf16(ka[mt][0], aq[ns][0], st, 0, 0, 0);
                    st = __builtin_amdgcn_mfma_f32_16x16x32_bf16(ka[mt][1], aq[ns][1], st, 0, 0, 0);
                    if (diag) {
#pragma unroll
                        for (int r = 0; r < 4; ++r)
                            if (half * 64 + mt * 16 + quad * 4 + r > qw + ns * 16 + l15)
                                st[r] = -INFINITY;
                    }
                    float e0 = fast_exp2(st[0]), e1 = fast_exp2(st[1]);
                    float e2 = fast_exp2(st[2]), e3 = fast_exp2(st[3]);
                    lsum[ns] += (e0 + e1) + (e2 + e3);
                    int2 pk;
                    pk.x = (int)((__float_as_uint(e0) >> 16) | (__float_as_uint(e1) & 0xffff0000u));
                    pk.y = (int)((__float_as_uint(e2) >> 16) | (__float_as_uint(e3) & 0xffff0000u));
                    *(int2*)&Ps[w][(ns * 16 + l15) * 72 + mt * 16 + quad * 4] = pk;
                }
            }
            // ---- O += P @ V: bv frags direct from V^T global ----
#pragma unroll
            for (int c2 = 0; c2 < 2; ++c2) {
                s8v ap0 = *(const s8v*)&Ps[w][l15 * 72 + c2 * 32 + quad * 8];
                s8v ap1 = *(const s8v*)&Ps[w][(16 + l15) * 72 + c2 * 32 + quad * 8];
                s8v bv[4];
#pragma unroll
                for (int nt = 0; nt < 4; ++nt)
                    bv[nt] = *(const s8v*)&vbase[(size_t)(nt * 16 + l15) * SEQ
                                                 + k0 + half * 64 + c2 * 32 + quad * 8];
#pragma unroll
                for (int nt = 0; nt < 4; ++nt) {
                    Oacc[0][nt] = __builtin_amdgcn_mfma_f32_16x16x32_bf16(
                        ap0, bv[nt], Oacc[0][nt], 0, 0, 0);
                    Oacc[1][nt] = __builtin_amdgcn_mfma_f32_16x16x32_bf16(
                        ap1, bv[nt], Oacc[1][nt], 0, 0, 0);
                }
            }
        }
    }

    // ---- write UNNORMALIZED partials: l (fp32) + O (bf16) ----
#pragma unroll
    for (int ns = 0; ns < 2; ++ns) {
        lsum[ns] += __shfl_xor(lsum[ns], 16, 64);
        lsum[ns] += __shfl_xor(lsum[ns], 32, 64);
    }
    float* L = Lp + ((size_t)seg << 16) + (size_t)bh * SEQ;
    if (quad == 0) {
        L[q0 + qw + l15]      = lsum[0];
        L[q0 + qw + 16 + l15] = lsum[1];
    }
    short* Op = (seg ? Op1 : Op0) + (size_t)bh * SEQ * D_HEAD;
#pragma unroll
    for (int ms = 0; ms < 2; ++ms)
#pragma unroll
        for (int r = 0; r < 4; ++r) {
            const int nloc = q0 + qw + ms * 16 + quad * 4 + r;
            short* dst = Op + (size_t)nloc * D_HEAD + l15;
#pragma unroll
            for (int nt = 0; nt < 4; ++nt)
                dst[nt * 16] = to_bf(Oacc[ms][nt][r]);
        }
}

// ---------------------------------------------------------------------------
// O-projection with FUSED combine (unchanged): 128M x 64N, grid 512.
// ---------------------------------------------------------------------------
__global__ __launch_bounds__(256) void gemm_oproj(
    const short* __restrict__ Op0, const short* __restrict__ Op1,
    const float* __restrict__ Lp, const short* __restrict__ Wob,
    const float* __restrict__ bo, float* __restrict__ out)
{
    __shared__ __align__(16) short As[128 * 64];   // 16 KB
    __shared__ __align__(16) short Bs[64 * 64];    //  8 KB
    __shared__ float invL[NUM_HEADS * 128];        //  8 KB: inv[h][row]

    const int t    = threadIdx.x;
    const int w    = t >> 6;
    const int lane = t & 63;
    const int quad = lane >> 4;
    const int l15  = lane & 15;
    const int wm   = w & 1, wn = w >> 1;

    const int n0 = blockIdx.x * 64;
    const int m0 = blockIdx.y * 128;
    const int bb = m0 >> 11, sloc = m0 & (SEQ - 1);

#pragma unroll
    for (int ii = 0; ii < 8; ++ii) {
        const int idx = t * 8 + ii;
        const int hh = idx >> 7, sl = idx & 127;
        const size_t loff = (size_t)(bb * NUM_HEADS + hh) * SEQ + sloc + sl;
        invL[idx] = 1.f / (Lp[loff] + Lp[65536 + loff]);
    }
    __syncthreads();

    f4v acc[4][2];
#pragma unroll
    for (int i = 0; i < 4; ++i)
#pragma unroll
        for (int j = 0; j < 2; ++j) acc[i][j] = (f4v){0.f, 0.f, 0.f, 0.f};

    for (int k0 = 0; k0 < D_MODEL; k0 += 64) {
        const int h = k0 >> 6;
#pragma unroll
        for (int i = 0; i < 2; ++i) {
            const int cid = i * 256 + w * 64 + lane;
            const int row = cid >> 3, pp = cid & 7, g = pp ^ (row & 7);
            gld_lds16(&Wob[(size_t)(n0 + row) * D_MODEL + k0 + g * 8],
                      &Bs[(i * 256 + w * 64) * 8]);
        }
        const size_t obase = ((size_t)(bb * NUM_HEADS + h) * SEQ + sloc) * D_HEAD;
#pragma unroll
        for (int i = 0; i < 4; ++i) {
            const int cid = i * 256 + t;
            const int row = cid >> 3, pp = cid & 7, g = pp ^ (row & 7);
            const size_t off = obase + (size_t)row * D_HEAD + g * 8;
            int4 a0 = *(const int4*)&Op0[off];
            int4 a1 = *(const int4*)&Op1[off];
            const float inv = invL[h * 128 + row];
            const unsigned* u0 = (const unsigned*)&a0;
            const unsigned* u1 = (const unsigned*)&a1;
            int4 o;
#pragma unroll
            for (int d = 0; d < 4; ++d) {
                float lo = (__uint_as_float(u0[d] << 16) +
                            __uint_as_float(u1[d] << 16)) * inv;
                float hi = (__uint_as_float(u0[d] & 0xffff0000u) +
                            __uint_as_float(u1[d] & 0xffff0000u)) * inv;
                ((unsigned*)&o)[d] = (__float_as_uint(lo) >> 16) |
                                     (__float_as_uint(hi) & 0xffff0000u);
            }
            *(int4*)&As[cid * 8] = o;
        }
        __syncthreads();

#pragma unroll
        for (int c = 0; c < 2; ++c) {
            s8v af[4], bf[2];
            const int pos = ((c * 4 + quad) ^ (l15 & 7)) * 8;
#pragma unroll
            for (int mi = 0; mi < 4; ++mi)
                af[mi] = *(const s8v*)&As[(wm * 64 + mi * 16 + l15) * 64 + pos];
#pragma unroll
            for (int ni = 0; ni < 2; ++ni)
                bf[ni] = *(const s8v*)&Bs[(wn * 32 + ni * 16 + l15) * 64 + pos];
#pragma unroll
            for (int mi = 0; mi < 4; ++mi)
#pragma unroll
                for (int ni = 0; ni < 2; ++ni)
                    acc[mi][ni] = __builtin_amdgcn_mfma_f32_16x16x32_bf16(
                        af[mi], bf[ni], acc[mi][ni], 0, 0, 0);
        }
        __syncthreads();
    }

#pragma unroll
    for (int ni = 0; ni < 2; ++ni) {
        const int col = n0 + wn * 32 + ni * 16 + l15;
        const float bv = bo[col];
#pragma unroll
        for (int mi = 0; mi < 4; ++mi)
#pragma unroll
            for (int r = 0; r < 4; ++r) {
                const int row = m0 + wm * 64 + mi * 16 + quad * 4 + r;
                out[(size_t)row * D_MODEL + col] = acc[mi][ni][r] + bv;
            }
    }
}

// ---------------------------------------------------------------------------
extern "C" void kernel_launch(void* const* d_in, const int* in_sizes, int n_in,
                              void* d_out, int out_size, void* d_ws, size_t ws_size,
                              hipStream_t stream)
{
    const float* x  = (const float*)d_in[0];
    const float* Wq = (const float*)d_in[1];
    const float* bq = (const float*)d_in[2];
    const float* Wk = (const float*)d_in[3];
    const float* bk = (const float*)d_in[4];
    const float* Wv = (const float*)d_in[5];
    const float* bv = (const float*)d_in[6];
    const float* Wo = (const float*)d_in[7];
    const float* bo = (const float*)d_in[8];
    float* out = (float*)d_out;

    short* wsp = (short*)d_ws;
    const size_t MAT = (size_t)NROWS * D_MODEL;   // 4 Mi elements
    short* Qb    = wsp;                           // [ 0, 8) MB  bf16 Q (exp2 scale)
    short* Kbg   = Qb + MAT;                      // [ 8,16) MB  bf16 K
    short* Vtb   = Kbg + MAT;                     // [16,24) MB  bf16 V^T
    short* Xb    = Vtb + 2 * MAT;                 // [32,40) MB  bf16 x (dead after QKV)
    short* Wqkvb = Xb + MAT;                      // [40,46) MB
    short* Wob   = Wqkvb + 3 * D_MODEL * D_MODEL; // [46,48) MB
    short* Op0   = Xb;                            // seg0 partial O aliases Xb
    short* Op1   = Wob + D_MODEL * D_MODEL;       // [48,56) MB
    float* Lp    = (float*)(Op1 + MAT);           // [56,56.5) MB: 2 x 64K floats

    cvt_fused<<<8192, 256, 0, stream>>>(x, Wq, Wk, Wv, Wo, Xb, Wqkvb, Wob);

    gemm_qkv<<<768, 256, 0, stream>>>(Xb, Wqkvb, bq, bk, bv, Qb, Kbg, Vtb);

    attn_mfma<<<1024, 256, 0, stream>>>(Qb, Kbg, Vtb, Op0, Op1, Lp);

    gemm_oproj<<<dim3(D_MODEL / 64, NROWS / 128), 256, 0, stream>>>(
        Op0, Op1, Lp, Wob, bo, out);
}

// Round 12
// 207.306 us; speedup vs baseline: 1.0890x; 1.0890x over previous
//
#include <hip/hip_runtime.h>
#include <math.h>

#define D_MODEL 1024
#define NUM_HEADS 16
#define D_HEAD 64
#define SEQ 2048
#define BATCH 2
#define NROWS (BATCH * SEQ) /* 4096 */

typedef short s8v __attribute__((ext_vector_type(8)));   // 8 bf16 (4 VGPRs)
typedef float f4v __attribute__((ext_vector_type(4)));   // MFMA C/D

__device__ __forceinline__ short to_bf(float f) {
    union { float f; unsigned u; } x; x.f = f;
    unsigned r = x.u + 0x7fffu + ((x.u >> 16) & 1u);   // RNE
    return (short)(r >> 16);
}

__device__ __forceinline__ unsigned pack_bf2(float a, float b) {
    return (unsigned)(unsigned short)to_bf(a) | ((unsigned)(unsigned short)to_bf(b) << 16);
}

// raw v_exp_f32 (exp2): 1 instruction vs OCML exp2f's denormal-fixup path
__device__ __forceinline__ float fast_exp2(float x) {
    return __builtin_amdgcn_exp2f(x);
}

// async global->LDS, 16 B/lane; LDS dest is wave-uniform base + lane*16
__device__ __forceinline__ void gld_lds16(const short* g, short* l) {
    __builtin_amdgcn_global_load_lds(
        (const __attribute__((address_space(1))) unsigned*)g,
        (__attribute__((address_space(3))) unsigned*)l, 16, 0, 0);
}

// Q pre-scale: 1/sqrt(Dh) * log2(e)  -> S leaves MFMA in exp2 domain
#define QSCALE 0.180336880f

// ---------------------------------------------------------------------------
// fp32 -> bf16 convert. Wq segment pre-scaled by QSCALE.
// ---------------------------------------------------------------------------
__global__ __launch_bounds__(256) void cvt_fused(
    const float* __restrict__ x,  const float* __restrict__ Wq,
    const float* __restrict__ Wk, const float* __restrict__ Wv,
    const float* __restrict__ Wo,
    short* __restrict__ Xb, short* __restrict__ Wqkvb, short* __restrict__ Wob)
{
    const int NX = NROWS * D_MODEL / 4;
    const int NW = D_MODEL * D_MODEL / 4;
    int j = blockIdx.x * 256 + threadIdx.x;
    const float* src; short* dst; float sc = 1.f;
    if (j < NX)                 { src = x;  dst = Xb; }
    else if ((j -= NX) < NW)    { src = Wq; dst = Wqkvb; sc = QSCALE; }
    else if ((j -= NW) < NW)    { src = Wk; dst = Wqkvb + NW * 4; }
    else if ((j -= NW) < NW)    { src = Wv; dst = Wqkvb + NW * 8; }
    else                        { j -= NW; src = Wo; dst = Wob; }
    float4 v = ((const float4*)src)[j];
    short4 s = { to_bf(v.x * sc), to_bf(v.y * sc), to_bf(v.z * sc), to_bf(v.w * sc) };
    ((short4*)dst)[j] = s;
}

// ---------------------------------------------------------------------------
// QKV bf16 MFMA GEMM (unchanged from R10): 128x128, BK=64, XOR-swizzled LDS,
// XCD-locality grid (768 blocks).  Q/K: transposed accumulate -> direct 8-B
// stores into [B,H,S,Dh].  V: normal -> direct stores into V^T [B,H,Dh,S].
// ---------------------------------------------------------------------------
__global__ __launch_bounds__(256) void gemm_qkv(
    const short* __restrict__ Xb, const short* __restrict__ Wb,
    const float* __restrict__ B0, const float* __restrict__ B1, const float* __restrict__ B2,
    short* __restrict__ Q0, short* __restrict__ K1, short* __restrict__ V2)
{
    __shared__ __align__(16) short As[128 * 64];   // 16 KB
    __shared__ __align__(16) short Bs[128 * 64];   // 16 KB

    const int t    = threadIdx.x;
    const int w    = t >> 6;
    const int lane = t & 63;
    const int quad = lane >> 4;
    const int l15  = lane & 15;
    const int wm   = w & 1, wn = w >> 1;

    const int bx    = blockIdx.x;
    const int xcd   = bx & 7;
    const int g_    = bx >> 3;            // 0..95
    const int n_loc = g_ % 12;
    const int m_loc = g_ / 12;            // 0..7
    const int n0 = ((xcd >> 2) * 12 + n_loc) * 128;
    const int m0 = ((xcd & 3) * 8 + m_loc) * 128;

    const bool swapT = (n0 < 2048);       // Q/K -> transposed accumulate

    f4v acc[4][4];
#pragma unroll
    for (int i = 0; i < 4; ++i)
#pragma unroll
        for (int j = 0; j < 4; ++j) acc[i][j] = (f4v){0.f, 0.f, 0.f, 0.f};

    for (int k0 = 0; k0 < D_MODEL; k0 += 64) {
#pragma unroll
        for (int i = 0; i < 4; ++i) {
            const int cid = i * 256 + t;
            const int row = cid >> 3, kc = cid & 7, g = kc ^ (row & 7);
            gld_lds16(&Xb[(size_t)(m0 + row) * D_MODEL + k0 + g * 8],
                      &As[(i * 256 + w * 64) * 8]);
            gld_lds16(&Wb[(size_t)(n0 + row) * D_MODEL + k0 + g * 8],
                      &Bs[(i * 256 + w * 64) * 8]);
        }
        __syncthreads();

#pragma unroll
        for (int c = 0; c < 2; ++c) {
            s8v af[4], bf[4];
            const int pos = ((c * 4 + quad) ^ (l15 & 7)) * 8;
#pragma unroll
            for (int mi = 0; mi < 4; ++mi)
                af[mi] = *(const s8v*)&As[(wm * 64 + mi * 16 + l15) * 64 + pos];
#pragma unroll
            for (int ni = 0; ni < 4; ++ni)
                bf[ni] = *(const s8v*)&Bs[(wn * 64 + ni * 16 + l15) * 64 + pos];
            if (swapT) {
#pragma unroll
                for (int mi = 0; mi < 4; ++mi)
#pragma unroll
                    for (int ni = 0; ni < 4; ++ni)
                        acc[mi][ni] = __builtin_amdgcn_mfma_f32_16x16x32_bf16(
                            bf[ni], af[mi], acc[mi][ni], 0, 0, 0);
            } else {
#pragma unroll
                for (int mi = 0; mi < 4; ++mi)
#pragma unroll
                    for (int ni = 0; ni < 4; ++ni)
                        acc[mi][ni] = __builtin_amdgcn_mfma_f32_16x16x32_bf16(
                            af[mi], bf[ni], acc[mi][ni], 0, 0, 0);
            }
        }
        __syncthreads();
    }

    if (swapT) {
        const int sel = n0 >> 10;                   // 0 or 1
        const float* bias = sel == 0 ? B0 : B1;
        short* out        = sel == 0 ? Q0 : K1;
        const float bsc   = sel == 0 ? QSCALE : 1.f;
        const int nb = n0 & 1023;
#pragma unroll
        for (int ni = 0; ni < 4; ++ni) {
            const int colb = nb + wn * 64 + ni * 16 + quad * 4;   // 4-aligned
            float4 bv = *(const float4*)&bias[colb];
            const int h = colb >> 6, dh = colb & 63;
#pragma unroll
            for (int mi = 0; mi < 4; ++mi) {
                const int row = m0 + wm * 64 + mi * 16 + l15;
                const int bb = row >> 11, sl = row & (SEQ - 1);
                int2 pk;
                pk.x = (int)pack_bf2(acc[mi][ni][0] + bv.x * bsc,
                                     acc[mi][ni][1] + bv.y * bsc);
                pk.y = (int)pack_bf2(acc[mi][ni][2] + bv.z * bsc,
                                     acc[mi][ni][3] + bv.w * bsc);
                *(int2*)&out[(((size_t)(bb * NUM_HEADS + h) * SEQ) + sl) * D_HEAD + dh] = pk;
            }
        }
    } else {
        const int nb = n0 & 1023;
#pragma unroll
        for (int ni = 0; ni < 4; ++ni) {
            const int col = nb + wn * 64 + ni * 16 + l15;
            const int h = col >> 6, dh = col & 63;
            const float bv = B2[col];
#pragma unroll
            for (int mi = 0; mi < 4; ++mi) {
                const int row = m0 + wm * 64 + mi * 16 + quad * 4;
                const int bb = row >> 11, sl = row & (SEQ - 1);
                int2 pk;
                pk.x = (int)pack_bf2(acc[mi][ni][0] + bv, acc[mi][ni][1] + bv);
                pk.y = (int)pack_bf2(acc[mi][ni][2] + bv, acc[mi][ni][3] + bv);
                *(int2*)&V2[((size_t)(bb * NUM_HEADS + h) * D_HEAD + dh) * SEQ + sl] = pk;
            }
        }
    }
}

// ---------------------------------------------------------------------------
// MFMA flash attention v8: LDS-staged (cross-wave sharing restored) with a
// DISTANCE-1 DMA PIPELINE.  64-key tiles, double-buffered K/V LDS, ONE
// barrier per tile ordered as: barrier -> issue DMA(tile i+1 -> other buf)
// -> compute(tile i).  The vmcnt(0) drain at the next barrier then waits on
// a DMA that has had a full compute phase in flight (cheap), instead of
// R10's zero-distance issue->drain.  Fully-masked subtiles skip compute.
// Key-split flash-decoding, 1024 blocks, fixed-shift additive partials.
// ---------------------------------------------------------------------------
__global__ __launch_bounds__(256) void attn_mfma(
    const short* __restrict__ Qg, const short* __restrict__ Kg,
    const short* __restrict__ Vg,
    short* __restrict__ Op0, short* __restrict__ Op1, float* __restrict__ Lp)
{
    __shared__ __align__(16) short Kb[2][64 * 64];   // 2 x 8 KB  [key][dh]
    __shared__ __align__(16) short Vs[2][64 * 64];   // 2 x 8 KB  [dh][key]
    __shared__ __align__(16) short Ps[4][32 * 72];   // 18 KB, per-wave [q][key64]

    const int t    = threadIdx.x;
    const int w    = t >> 6;
    const int lane = t & 63;
    const int quad = lane >> 4;
    const int l15  = lane & 15;

    const int bidx = blockIdx.x;
    const int seg  = bidx >> 9;               // key parity (128-tile granularity)
    const int p    = bidx & 255;
    const int bh   = p >> 3;
    const int pair = p & 7;
    const int qt   = ((bidx >> 8) & 1) ? 15 - pair : pair;

    const short* qbase = Qg + (size_t)bh * SEQ * D_HEAD;
    const short* kbase = Kg + (size_t)bh * SEQ * D_HEAD;
    const short* vbase = Vg + (size_t)bh * D_HEAD * SEQ;
    const int q0 = qt * 128;
    const int qw = w * 32;

    // Q fragments (B-operand layout: lane = query, regs = d). QSCALE pre-folded.
    s8v aq[2][2];
#pragma unroll
    for (int ns = 0; ns < 2; ++ns)
#pragma unroll
        for (int c = 0; c < 2; ++c)
            aq[ns][c] = *(const s8v*)&qbase[(size_t)(q0 + qw + ns * 16 + l15) * D_HEAD
                                            + c * 32 + quad * 8];

    f4v Oacc[2][4];
#pragma unroll
    for (int ms = 0; ms < 2; ++ms)
#pragma unroll
        for (int nt = 0; nt < 4; ++nt) Oacc[ms][nt] = (f4v){0.f, 0.f, 0.f, 0.f};
    float lsum[2] = {0.f, 0.f};

    // 64-key subtiles of the 128-key tiles j = seg, seg+2, ... <= qt
    const int niter = (qt >= seg) ? ((((qt - seg) >> 1) + 1) * 2) : 0;

    // stage tile (key base k0) into buffer b: K 512 chunks + V 512 chunks,
    // 2 DMA pairs per thread, XOR-swizzled (LDS slot (row,pp) <- chunk pp^(row&7))
#define STAGE(k0_, b_)                                                          \
    {                                                                           \
        const int kk = (k0_);                                                   \
_Pragma("unroll")                                                               \
        for (int u = 0; u < 2; ++u) {                                           \
            const int cid = u * 256 + w * 64 + lane;                            \
            const int row = cid >> 3, pp = cid & 7, g = pp ^ (row & 7);         \
            gld_lds16(&kbase[(size_t)(kk + row) * D_HEAD + g * 8],              \
                      &Kb[b_][(u * 256 + w * 64) * 8]);                         \
            gld_lds16(&vbase[(size_t)row * SEQ + kk + g * 8],                   \
                      &Vs[b_][(u * 256 + w * 64) * 8]);                         \
        }                                                                       \
    }

    if (niter > 0) STAGE(seg * 128, 0);   // prologue: tile 0 -> buf 0

    for (int i = 0; i < niter; ++i) {
        __syncthreads();   // drains DMA of tile i (issued one full iter ago)

        if (i + 1 < niter) {
            const int i1 = i + 1;
            const int k1 = (seg + 2 * (i1 >> 1)) * 128 + (i1 & 1) * 64;
            STAGE(k1, i1 & 1);   // in flight across the whole compute below
        }

        const int k0   = (seg + 2 * (i >> 1)) * 128 + (i & 1) * 64;
        const int b    = i & 1;
        const int koff = k0 - q0;
        if (koff > qw + 31) continue;          // all keys > all queries: skip
        const bool diag = (koff + 63 > qw);

        // ---- K-frags from LDS; S^T = K·Q^T (exp2 domain); exp; pack; Ps ----
#pragma unroll
        for (int mt = 0; mt < 4; ++mt) {
            const int krow = mt * 16 + l15;
            s8v ka0 = *(const s8v*)&Kb[b][(krow * 8 + ((quad) ^ (l15 & 7))) * 8];
            s8v ka1 = *(const s8v*)&Kb[b][(krow * 8 + ((4 + quad) ^ (l15 & 7))) * 8];
#pragma unroll
            for (int ns = 0; ns < 2; ++ns) {
                f4v st = (f4v){0.f, 0.f, 0.f, 0.f};
                st = __builtin_amdgcn_mfma_f32_16x16x32_bf16(ka0, aq[ns][0], st, 0, 0, 0);
                st = __builtin_amdgcn_mfma_f32_16x16x32_bf16(ka1, aq[ns][1], st, 0, 0, 0);
                if (diag) {
#pragma unroll
                    for (int r = 0; r < 4; ++r)
                        if (koff + mt * 16 + quad * 4 + r > qw + ns * 16 + l15)
                            st[r] = -INFINITY;
                }
                float e0 = fast_exp2(st[0]), e1 = fast_exp2(st[1]);
                float e2 = fast_exp2(st[2]), e3 = fast_exp2(st[3]);
                lsum[ns] += (e0 + e1) + (e2 + e3);
                int2 pk;
                pk.x = (int)((__float_as_uint(e0) >> 16) | (__float_as_uint(e1) & 0xffff0000u));
                pk.y = (int)((__float_as_uint(e2) >> 16) | (__float_as_uint(e3) & 0xffff0000u));
                *(int2*)&Ps[w][(ns * 16 + l15) * 72 + mt * 16 + quad * 4] = pk;
            }
        }
        // ---- O += P @ V (Ps wave-private, in-order DS; V from LDS) ----
#pragma unroll
        for (int c2 = 0; c2 < 2; ++c2) {
            s8v ap0 = *(const s8v*)&Ps[w][l15 * 72 + c2 * 32 + quad * 8];
            s8v ap1 = *(const s8v*)&Ps[w][(16 + l15) * 72 + c2 * 32 + quad * 8];
            s8v bv[4];
#pragma unroll
            for (int nt = 0; nt < 4; ++nt) {
                const int vrow = nt * 16 + l15;
                bv[nt] = *(const s8v*)&Vs[b][(vrow * 8 + ((c2 * 4 + quad) ^ (l15 & 7))) * 8];
            }
#pragma unroll
            for (int nt = 0; nt < 4; ++nt) {
                Oacc[0][nt] = __builtin_amdgcn_mfma_f32_16x16x32_bf16(
                    ap0, bv[nt], Oacc[0][nt], 0, 0, 0);
                Oacc[1][nt] = __builtin_amdgcn_mfma_f32_16x16x32_bf16(
                    ap1, bv[nt], Oacc[1][nt], 0, 0, 0);
            }
        }
    }
#undef STAGE

    // ---- write UNNORMALIZED partials: l (fp32) + O (bf16) ----
#pragma unroll
    for (int ns = 0; ns < 2; ++ns) {
        lsum[ns] += __shfl_xor(lsum[ns], 16, 64);
        lsum[ns] += __shfl_xor(lsum[ns], 32, 64);
    }
    float* L = Lp + ((size_t)seg << 16) + (size_t)bh * SEQ;
    if (quad == 0) {
        L[q0 + qw + l15]      = lsum[0];
        L[q0 + qw + 16 + l15] = lsum[1];
    }
    short* Op = (seg ? Op1 : Op0) + (size_t)bh * SEQ * D_HEAD;
#pragma unroll
    for (int ms = 0; ms < 2; ++ms)
#pragma unroll
        for (int r = 0; r < 4; ++r) {
            const int nloc = q0 + qw + ms * 16 + quad * 4 + r;
            short* dst = Op + (size_t)nloc * D_HEAD + l15;
#pragma unroll
            for (int nt = 0; nt < 4; ++nt)
                dst[nt * 16] = to_bf(Oacc[ms][nt][r]);
        }
}

// ---------------------------------------------------------------------------
// O-projection with FUSED combine (unchanged): 128M x 64N, grid 512.
// ---------------------------------------------------------------------------
__global__ __launch_bounds__(256) void gemm_oproj(
    const short* __restrict__ Op0, const short* __restrict__ Op1,
    const float* __restrict__ Lp, const short* __restrict__ Wob,
    const float* __restrict__ bo, float* __restrict__ out)
{
    __shared__ __align__(16) short As[128 * 64];   // 16 KB
    __shared__ __align__(16) short Bs[64 * 64];    //  8 KB
    __shared__ float invL[NUM_HEADS * 128];        //  8 KB: inv[h][row]

    const int t    = threadIdx.x;
    const int w    = t >> 6;
    const int lane = t & 63;
    const int quad = lane >> 4;
    const int l15  = lane & 15;
    const int wm   = w & 1, wn = w >> 1;

    const int n0 = blockIdx.x * 64;
    const int m0 = blockIdx.y * 128;
    const int bb = m0 >> 11, sloc = m0 & (SEQ - 1);

#pragma unroll
    for (int ii = 0; ii < 8; ++ii) {
        const int idx = t * 8 + ii;
        const int hh = idx >> 7, sl = idx & 127;
        const size_t loff = (size_t)(bb * NUM_HEADS + hh) * SEQ + sloc + sl;
        invL[idx] = 1.f / (Lp[loff] + Lp[65536 + loff]);
    }
    __syncthreads();

    f4v acc[4][2];
#pragma unroll
    for (int i = 0; i < 4; ++i)
#pragma unroll
        for (int j = 0; j < 2; ++j) acc[i][j] = (f4v){0.f, 0.f, 0.f, 0.f};

    for (int k0 = 0; k0 < D_MODEL; k0 += 64) {
        const int h = k0 >> 6;
#pragma unroll
        for (int i = 0; i < 2; ++i) {
            const int cid = i * 256 + w * 64 + lane;
            const int row = cid >> 3, pp = cid & 7, g = pp ^ (row & 7);
            gld_lds16(&Wob[(size_t)(n0 + row) * D_MODEL + k0 + g * 8],
                      &Bs[(i * 256 + w * 64) * 8]);
        }
        const size_t obase = ((size_t)(bb * NUM_HEADS + h) * SEQ + sloc) * D_HEAD;
#pragma unroll
        for (int i = 0; i < 4; ++i) {
            const int cid = i * 256 + t;
            const int row = cid >> 3, pp = cid & 7, g = pp ^ (row & 7);
            const size_t off = obase + (size_t)row * D_HEAD + g * 8;
            int4 a0 = *(const int4*)&Op0[off];
            int4 a1 = *(const int4*)&Op1[off];
            const float inv = invL[h * 128 + row];
            const unsigned* u0 = (const unsigned*)&a0;
            const unsigned* u1 = (const unsigned*)&a1;
            int4 o;
#pragma unroll
            for (int d = 0; d < 4; ++d) {
                float lo = (__uint_as_float(u0[d] << 16) +
                            __uint_as_float(u1[d] << 16)) * inv;
                float hi = (__uint_as_float(u0[d] & 0xffff0000u) +
                            __uint_as_float(u1[d] & 0xffff0000u)) * inv;
                ((unsigned*)&o)[d] = (__float_as_uint(lo) >> 16) |
                                     (__float_as_uint(hi) & 0xffff0000u);
            }
            *(int4*)&As[cid * 8] = o;
        }
        __syncthreads();

#pragma unroll
        for (int c = 0; c < 2; ++c) {
            s8v af[4], bf[2];
            const int pos = ((c * 4 + quad) ^ (l15 & 7)) * 8;
#pragma unroll
            for (int mi = 0; mi < 4; ++mi)
                af[mi] = *(const s8v*)&As[(wm * 64 + mi * 16 + l15) * 64 + pos];
#pragma unroll
            for (int ni = 0; ni < 2; ++ni)
                bf[ni] = *(const s8v*)&Bs[(wn * 32 + ni * 16 + l15) * 64 + pos];
#pragma unroll
            for (int mi = 0; mi < 4; ++mi)
#pragma unroll
                for (int ni = 0; ni < 2; ++ni)
                    acc[mi][ni] = __builtin_amdgcn_mfma_f32_16x16x32_bf16(
                        af[mi], bf[ni], acc[mi][ni], 0, 0, 0);
        }
        __syncthreads();
    }

#pragma unroll
    for (int ni = 0; ni < 2; ++ni) {
        const int col = n0 + wn * 32 + ni * 16 + l15;
        const float bv = bo[col];
#pragma unroll
        for (int mi = 0; mi < 4; ++mi)
#pragma unroll
            for (int r = 0; r < 4; ++r) {
                const int row = m0 + wm * 64 + mi * 16 + quad * 4 + r;
                out[(size_t)row * D_MODEL + col] = acc[mi][ni][r] + bv;
            }
    }
}

// ---------------------------------------------------------------------------
extern "C" void kernel_launch(void* const* d_in, const int* in_sizes, int n_in,
                              void* d_out, int out_size, void* d_ws, size_t ws_size,
                              hipStream_t stream)
{
    const float* x  = (const float*)d_in[0];
    const float* Wq = (const float*)d_in[1];
    const float* bq = (const float*)d_in[2];
    const float* Wk = (const float*)d_in[3];
    const float* bk = (const float*)d_in[4];
    const float* Wv = (const float*)d_in[5];
    const float* bv = (const float*)d_in[6];
    const float* Wo = (const float*)d_in[7];
    const float* bo = (const float*)d_in[8];
    float* out = (float*)d_out;

    short* wsp = (short*)d_ws;
    const size_t MAT = (size_t)NROWS * D_MODEL;   // 4 Mi elements
    short* Qb    = wsp;                           // [ 0, 8) MB  bf16 Q (exp2 scale)
    short* Kbg   = Qb + MAT;                      // [ 8,16) MB  bf16 K
    short* Vtb   = Kbg + MAT;                     // [16,24) MB  bf16 V^T
    short* Xb    = Vtb + 2 * MAT;                 // [32,40) MB  bf16 x (dead after QKV)
    short* Wqkvb = Xb + MAT;                      // [40,46) MB
    short* Wob   = Wqkvb + 3 * D_MODEL * D_MODEL; // [46,48) MB
    short* Op0   = Xb;                            // seg0 partial O aliases Xb
    short* Op1   = Wob + D_MODEL * D_MODEL;       // [48,56) MB
    float* Lp    = (float*)(Op1 + MAT);           // [56,56.5) MB: 2 x 64K floats

    cvt_fused<<<8192, 256, 0, stream>>>(x, Wq, Wk, Wv, Wo, Xb, Wqkvb, Wob);

    gemm_qkv<<<768, 256, 0, stream>>>(Xb, Wqkvb, bq, bk, bv, Qb, Kbg, Vtb);

    attn_mfma<<<1024, 256, 0, stream>>>(Qb, Kbg, Vtb, Op0, Op1, Lp);

    gemm_oproj<<<dim3(D_MODEL / 64, NROWS / 128), 256, 0, stream>>>(
        Op0, Op1, Lp, Wob, bo, out);
}